// Round 17
// baseline (1161.164 us; speedup 1.0000x reference)
//
#include <hip/hip_runtime.h>
#include <stdint.h>

// ---- problem constants ----
#define NBG   64      // graphs
#define NPER  32      // nodes per graph
#define DNODE 320
#define FEAT  1472
#define HIDN  2944
#define FEATP 1536    // FEAT padded to x128 for layer-2 N
#define NA    11
#define NROWS 2048    // NBG*NPER
#define MEDGE 65536   // NBG*NPER*NPER

typedef __attribute__((ext_vector_type(8))) short    bf16x8;
typedef __attribute__((ext_vector_type(4))) float    fv4;
typedef __attribute__((ext_vector_type(2))) float    fv2;
typedef __attribute__((ext_vector_type(4))) unsigned uiv4;

__device__ __forceinline__ unsigned short f2bf(float f) {
  unsigned u = __builtin_bit_cast(unsigned, f);
  u += 0x7fffu + ((u >> 16) & 1u);
  return (unsigned short)(u >> 16);
}
__device__ __forceinline__ float bf2f(unsigned short h) {
  unsigned u = ((unsigned)h) << 16;
  return __builtin_bit_cast(float, u);
}
__device__ __forceinline__ unsigned cvt_pk_bf16(float lo, float hi) {
  unsigned r;
  asm("v_cvt_pk_bf16_f32 %0, %1, %2" : "=v"(r) : "v"(lo), "v"(hi));
  return r;
}
// packed f32 add (VOP3P) — one instr for two adds
__device__ __forceinline__ fv2 pk_add(fv2 a, fv2 b) {
  fv2 d;
  asm("v_pk_add_f32 %0, %1, %2" : "=v"(d) : "v"(a), "v"(b));
  return d;
}
// relu on 2 packed bf16: positive bf16 sorts as positive i16; negative -> 0.
__device__ __forceinline__ unsigned pk_relu2(unsigned x, unsigned z) {
  unsigned r;
  asm("v_pk_max_i16 %0, %1, %2" : "=v"(r) : "v"(x), "v"(z));
  return r;
}
__device__ __forceinline__ fv2 lo2(fv4 v) { return __builtin_shufflevector(v, v, 0, 1); }
__device__ __forceinline__ fv2 hi2(fv4 v) { return __builtin_shufflevector(v, v, 2, 3); }
// async global->LDS, 16B per lane; lds base wave-uniform (HW adds lane*16)
__device__ __forceinline__ void gload_lds16(const void* g, void* l) {
  __builtin_amdgcn_global_load_lds((const __attribute__((address_space(1))) void*)g,
                                   (__attribute__((address_space(3))) void*)l, 16, 0, 0);
}

// ---- transpose f32 [K][N] -> bf16 [Npad][K]; rows n>=N zero-filled ----
__global__ void k_transpose_bf16(const float* __restrict__ src, unsigned short* __restrict__ dst,
                                 int K, int N, int Npad) {
  __shared__ float tile[64][65];
  int k0 = blockIdx.x * 64, n0 = blockIdx.y * 64;
  int r = threadIdx.x >> 2, cb = (threadIdx.x & 3) * 16;
  const float* srow = src + (size_t)(k0 + r) * N + n0 + cb;
#pragma unroll
  for (int c = 0; c < 16; ++c) {
    int n = n0 + cb + c;
    tile[r][cb + c] = (n < N) ? srow[c] : 0.f;
  }
  __syncthreads();
  unsigned short* drow = dst + (size_t)(n0 + r) * K + k0 + cb;
#pragma unroll
  for (int c = 0; c < 16; ++c) drow[c] = f2bf(tile[cb + c][r]);
}

// ---- embeddings -> xb bf16 [2048][320] ----
__global__ void k_embed(const int* __restrict__ idx, const int* __restrict__ mlt,
                        const float* __restrict__ id_emb, const float* __restrict__ mult_emb,
                        unsigned short* __restrict__ xb) {
  int t = blockIdx.x, c = threadIdx.x;
  int iv = idx[t], mv = mlt[t];
  xb[t * DNODE + c] = f2bf(id_emb[iv * 256 + c]);
  if (c < 64) xb[t * DNODE + 256 + c] = f2bf(mult_emb[mv * 64 + c]);
}

// ---- agg f32 [64][320] = mean over 32 nodes ----
__global__ void k_agg(const unsigned short* __restrict__ xb, float* __restrict__ agg) {
  int b = blockIdx.x;
  for (int d = threadIdx.x; d < DNODE; d += 256) {
    float s = 0.f;
    for (int i = 0; i < NPER; ++i) s += bf2f(xb[(b * NPER + i) * DNODE + d]);
    agg[b * DNODE + d] = s * (1.f / 32.f);
  }
}

// ---- za bf16 [128][832] = [z | agg], rows 64..127 zero ----
__global__ void k_za(const float* __restrict__ z, const float* __restrict__ agg,
                     unsigned short* __restrict__ za) {
  int b = blockIdx.x;
  for (int c = threadIdx.x; c < 832; c += 256) {
    unsigned short v = 0;
    if (b < NBG) v = (c < 512) ? f2bf(z[b * 512 + c]) : f2bf(agg[b * DNODE + (c - 512)]);
    za[b * 832 + c] = v;
  }
}

// ---- layer-1 GEMM: C[M][2944] (f32) = A(bf16,[M][sA] slice) @ W1T(bf16 [2944][1472])^T ----
__global__ void k_gemm1(const unsigned short* __restrict__ A, int sA, int Mrows,
                        const unsigned short* __restrict__ W1T, int kOff, int Ksteps,
                        float* __restrict__ C, const float* __restrict__ bias) {
  __shared__ alignas(16) unsigned short Als[128 * 32];
  __shared__ alignas(16) unsigned short Bls[128 * 32];
  int bx = blockIdx.x;
  int mt = bx / 23, nc = bx - mt * 23;
  int m0 = mt * 128, n0 = nc * 128;
  int tid = threadIdx.x, lane = tid & 63, w = tid >> 6;

  fv4 acc[4][4] = {};
  for (int kt = 0; kt < Ksteps; ++kt) {
    int k0 = kt * 32;
    __syncthreads();
#pragma unroll
    for (int q = 0; q < 2; ++q) {
      int seg = w * 2 + q;
      int row = seg * 16 + (lane >> 2);
      int col = (lane & 3) * 8;
      gload_lds16(A + (size_t)(m0 + row) * sA + k0 + col, &Als[seg * 512]);
      gload_lds16(W1T + (size_t)(n0 + row) * FEAT + kOff + k0 + col, &Bls[seg * 512]);
    }
    __syncthreads();
    bf16x8 aF[4], bF[4];
#pragma unroll
    for (int mf = 0; mf < 4; ++mf)
      aF[mf] = *(const bf16x8*)&Als[((w >> 1) * 64 + mf * 16 + (lane & 15)) * 32 + (lane >> 4) * 8];
#pragma unroll
    for (int nf = 0; nf < 4; ++nf)
      bF[nf] = *(const bf16x8*)&Bls[((w & 1) * 64 + nf * 16 + (lane & 15)) * 32 + (lane >> 4) * 8];
#pragma unroll
    for (int mf = 0; mf < 4; ++mf)
#pragma unroll
      for (int nf = 0; nf < 4; ++nf)
        acc[mf][nf] = __builtin_amdgcn_mfma_f32_16x16x32_bf16(aF[mf], bF[nf], acc[mf][nf], 0, 0, 0);
  }
  int mq = (w >> 1) * 64, nq = (w & 1) * 64;
#pragma unroll
  for (int mf = 0; mf < 4; ++mf)
#pragma unroll
    for (int nf = 0; nf < 4; ++nf) {
      int n = n0 + nq + nf * 16 + (lane & 15);
      float bv = bias ? bias[n] : 0.f;
#pragma unroll
      for (int r = 0; r < 4; ++r) {
        int m = m0 + mq + mf * 16 + (lane >> 4) * 4 + r;
        if (m < Mrows) C[(size_t)m * HIDN + n] = acc[mf][nf][r] + bv;
      }
    }
}

// ---- PQ1 = P1 + Q[b] (in place on P1; Q already includes b1) ----
__global__ void k_pq(float* __restrict__ P1, const float* __restrict__ Q) {
  int r = blockIdx.x;
  const float* q = Q + (size_t)(r >> 5) * HIDN;
  float* p = P1 + (size_t)r * HIDN;
  for (int n = threadIdx.x; n < HIDN; n += 256) p[n] += q[n];
}

__global__ void k_zero(float* __restrict__ p, int n) {
  int i = blockIdx.x * 256 + threadIdx.x;
  if (i < n) p[i] = 0.f;
}

// ---- layer-2 GEMM fused with layer-3 partial, N=256, pipelined A-construct ----
// R11/R16 champion with ONE change: cross-barrier register pipelining of the
// A-construct. TRIPLE-buffered LDS; at step kt the wave stages kt+2, ds_reads
// bF(kt) + the p/q operands for kt+1, runs MFMA(kt) from REGISTERS built last
// step (issue blocks only on the 8 bF reads, never on the 130-op construct),
// then builds aF(kt+1) on the VALU while the MFMA pipe drains. Two named
// register sets (aA/aB) swap roles via pair-unroll (no runtime indexing).
// Hazards unchanged: the full-drain __syncthreads guards both stage-overwrite
// (buffer last read at kt-1) and read-after-stage (data staged at kt-1).
// LDS: B[3][16384] @0 | P2s[3][4096] @49152 | PQ1s[3][1024] @61440 = 64512
// (2 blocks/CU: 129024 <= 163840)
__global__ __launch_bounds__(256, 2)
void k_gemm2(const float* __restrict__ PQ1, const float* __restrict__ P2,
             const unsigned short* __restrict__ W2T,
             const float* __restrict__ b2, const float* __restrict__ W3,
             float* __restrict__ Lout) {
  __shared__ alignas(16) unsigned char LB[64512];
  int raw = blockIdx.x;
  int g = (raw & 7) * 384 + (raw >> 3);   // bijective: 3072 = 8 * 384
  int nc2 = g / 512;                      // panel index: constant per XCD span
  int mt  = g - nc2 * 512;                // sequential m-tiles within a panel
  int m0 = mt * 128, n0 = nc2 * 256;
  int tid = threadIdx.x, lane = tid & 63, w = tid >> 6;
  int bG = m0 >> 10;
  int i0 = (m0 >> 5) & 31;
  int ks = lane >> 4;
  int r  = lane & 15;
  int il0 = (w >> 1) * 2;

  const int swcolB = ((lane & 3) ^ ((lane >> 3) & 3)) * 8;
  const int swcolP = (((lane >> 1) & 3) ^ ((lane >> 3) & 3)) * 8 + (lane & 1) * 4;

  auto STAGEB = [&](int kt, int buf) {
#pragma unroll
    for (int q = 0; q < 4; ++q) {
      int seg = w * 4 + q;
      int row = seg * 16 + (lane >> 2);
      gload_lds16(W2T + (size_t)(n0 + row) * HIDN + kt * 32 + swcolB,
                  LB + buf * 16384 + seg * 1024);
    }
  };
  auto STAGESRC = [&](int kt, int buf) {
    gload_lds16(P2 + (size_t)(bG * NPER + 8 * w + (lane >> 3)) * HIDN + kt * 32 + swcolP,
                LB + 49152 + buf * 4096 + w * 1024);
    if (w == 0)
      gload_lds16(PQ1 + (size_t)(bG * NPER + i0 + (lane >> 3)) * HIDN + kt * 32 + (lane & 7) * 4,
                  LB + 61440 + buf * 1024);
  };

  fv4 acc[4][8] = {};
  unsigned z0 = 0;
  asm volatile("" : "+v"(z0));   // keep zero in a VGPR for pk_max

  // construct aF for the data in buffer `buf` (p/q reads + packed math)
  auto CONSTRUCT = [&](int buf, bf16x8 (&aF)[4]) {
    const unsigned char* Pb = LB + 49152 + buf * 4096;
    const unsigned char* Qb = LB + 61440 + buf * 1024;
    int psw = (ks ^ (r & 3)) * 32;
    fv4 q0[2], q1[2], p0[2], p1[2];
#pragma unroll
    for (int h = 0; h < 2; ++h) {
      q0[h] = *(const fv4*)(Qb + il0 * 128 + ks * 32 + h * 16);        // broadcast
      q1[h] = *(const fv4*)(Qb + (il0 + 1) * 128 + ks * 32 + h * 16);  // broadcast
      p0[h] = *(const fv4*)(Pb + r * 128 + psw + h * 16);
      p1[h] = *(const fv4*)(Pb + (16 + r) * 128 + psw + h * 16);
    }
#pragma unroll
    for (int mf = 0; mf < 4; ++mf) {
      fv4 qa0 = (mf & 2) ? q1[0] : q0[0];
      fv4 qa1 = (mf & 2) ? q1[1] : q0[1];
      fv4 pa0 = (mf & 1) ? p1[0] : p0[0];
      fv4 pa1 = (mf & 1) ? p1[1] : p0[1];
      fv2 s00 = pk_add(lo2(qa0), lo2(pa0));
      fv2 s01 = pk_add(hi2(qa0), hi2(pa0));
      fv2 s10 = pk_add(lo2(qa1), lo2(pa1));
      fv2 s11 = pk_add(hi2(qa1), hi2(pa1));
      uiv4 u;
      u[0] = pk_relu2(cvt_pk_bf16(s00[0], s00[1]), z0);
      u[1] = pk_relu2(cvt_pk_bf16(s01[0], s01[1]), z0);
      u[2] = pk_relu2(cvt_pk_bf16(s10[0], s10[1]), z0);
      u[3] = pk_relu2(cvt_pk_bf16(s11[0], s11[1]), z0);
      aF[mf] = __builtin_bit_cast(bf16x8, u);
    }
  };

  // one K-step: MFMA from `cur` registers; build `nxt` for step kt+1
  auto STEP = [&](int kt, bf16x8 (&cur)[4], bf16x8 (&nxt)[4]) {
    if (kt < 90) {
      int sb = (kt + 2) % 3;
      STAGEB(kt + 2, sb);
      STAGESRC(kt + 2, sb);
    }
    // bF reads for THIS step (issued first -> MFMA waits only on these)
    const unsigned char* Bb = LB + (kt % 3) * 16384;
    bf16x8 bF[8];
#pragma unroll
    for (int nf = 0; nf < 8; ++nf) {
      int brow = (w & 1) * 128 + nf * 16 + r;
      int slot = ks ^ ((brow >> 1) & 3);
      bF[nf] = *(const bf16x8*)(Bb + brow * 64 + slot * 16);
    }
    // MFMA from registers built LAST step (no dependence on this step's construct)
#pragma unroll
    for (int nf = 0; nf < 8; ++nf)
#pragma unroll
      for (int mf = 0; mf < 4; ++mf)
        acc[mf][nf] = __builtin_amdgcn_mfma_f32_16x16x32_bf16(cur[mf], bF[nf], acc[mf][nf], 0, 0, 0);
    // build aF for step kt+1 (VALU, overlaps MFMA pipe drain)
    if (kt < 91) CONSTRUCT((kt + 1) % 3, nxt);
    __syncthreads();
  };

  // prologue: stage steps 0 and 1; drain; build aF(0) from buf 0
  STAGEB(0, 0); STAGESRC(0, 0);
  STAGEB(1, 1); STAGESRC(1, 1);
  __syncthreads();

  bf16x8 aA[4], aB[4];
  CONSTRUCT(0, aA);

  for (int kt = 0; kt < 92; kt += 2) {
    STEP(kt, aA, aB);
    STEP(kt + 1, aB, aA);
  }

  // epilogue: h2 = relu(acc + b2); partial logits = h2 @ W3 chunk (128 n-cols
  // per wave); wave shfl reduce; cross-wave LDS reduce; atomicAdd.
  float* red = (float*)LB;
  int nq = (w & 1) * 128;
#pragma unroll
  for (int mf = 0; mf < 4; ++mf) {
    float s[4][NA];
#pragma unroll
    for (int rr = 0; rr < 4; ++rr)
#pragma unroll
      for (int a = 0; a < NA; ++a) s[rr][a] = 0.f;
#pragma unroll
    for (int nf = 0; nf < 8; ++nf) {
      int n = n0 + nq + nf * 16 + r;
      if (n < FEAT) {  // boundary multiple of 16 -> uniform per nf
        float bv = b2[n];
        float w3r[NA];
#pragma unroll
        for (int a = 0; a < NA; ++a) w3r[a] = W3[n * NA + a];
#pragma unroll
        for (int rr = 0; rr < 4; ++rr) {
          float h = fmaxf(acc[mf][nf][rr] + bv, 0.f);
#pragma unroll
          for (int a = 0; a < NA; ++a) s[rr][a] += h * w3r[a];
        }
      }
    }
#pragma unroll
    for (int off = 1; off < 16; off <<= 1)
#pragma unroll
      for (int rr = 0; rr < 4; ++rr)
#pragma unroll
        for (int a = 0; a < NA; ++a) s[rr][a] += __shfl_xor(s[rr][a], off, 64);
    int a = r;
    if (a < NA) {
#pragma unroll
      for (int rr = 0; rr < 4; ++rr)
        red[w * 704 + (mf * 16 + ks * 4 + rr) * NA + a] = s[rr][a];
    }
  }
  __syncthreads();
  for (int e = tid; e < 128 * NA; e += 256) {
    int row = e / NA, a = e - row * NA;
    int wr = row >> 6, rr = row & 63;
    float v = red[(wr * 2 + 0) * 704 + rr * NA + a] + red[(wr * 2 + 1) * 704 + rr * NA + a];
    atomicAdd(&Lout[(size_t)(m0 + row) * NA + a], v);
  }
}

// ---- symmetrize + b3 ----
__global__ void k_sym(const float* __restrict__ Lraw, const float* __restrict__ b3,
                      float* __restrict__ out) {
  int e = blockIdx.x * 256 + threadIdx.x;
  if (e >= MEDGE * NA) return;
  int m = e / NA, a = e - m * NA;
  int msw = (m & ~1023) | ((m & 31) << 5) | ((m >> 5) & 31);
  out[e] = 0.5f * (Lraw[e] + Lraw[(size_t)msw * NA + a]) + b3[a];
}

extern "C" void kernel_launch(void* const* d_in, const int* in_sizes, int n_in,
                              void* d_out, int out_size, void* d_ws, size_t ws_size,
                              hipStream_t stream) {
  const int*   idx      = (const int*)d_in[0];
  const int*   mlt      = (const int*)d_in[1];
  const float* z        = (const float*)d_in[2];
  const float* id_emb   = (const float*)d_in[3];
  const float* mult_emb = (const float*)d_in[4];
  const float* W1       = (const float*)d_in[5];
  const float* b1       = (const float*)d_in[6];
  const float* W2       = (const float*)d_in[7];
  const float* b2       = (const float*)d_in[8];
  const float* W3       = (const float*)d_in[9];
  const float* b3       = (const float*)d_in[10];
  float* out = (float*)d_out;

  uint8_t* ws = (uint8_t*)d_ws;
  size_t o = 0;
  auto alloc = [&](size_t bytes) { size_t r = o; o += (bytes + 255) & ~(size_t)255; return r; };
  size_t oW1T = alloc((size_t)HIDN * FEAT * 2);       // bf16 [2944][1472]
  size_t oW2T = alloc((size_t)FEATP * HIDN * 2);      // bf16 [1536][2944]
  size_t oXB  = alloc((size_t)NROWS * DNODE * 2);     // bf16 [2048][320]
  size_t oZA  = alloc((size_t)128 * 832 * 2);         // bf16 [128][832]
  size_t oAG  = alloc((size_t)NBG * DNODE * 4);       // f32  [64][320]
  size_t oP1  = alloc((size_t)NROWS * HIDN * 4);      // f32  [2048][2944]
  size_t oP2  = alloc((size_t)NROWS * HIDN * 4);
  size_t oQ   = alloc((size_t)NBG * HIDN * 4);
  size_t oLR  = alloc((size_t)MEDGE * NA * 4);        // single f32 slice
  if (ws_size < o) return;  // insufficient workspace (71.2 MB, known to fit)

  unsigned short* W1T = (unsigned short*)(ws + oW1T);
  unsigned short* W2T = (unsigned short*)(ws + oW2T);
  unsigned short* xb  = (unsigned short*)(ws + oXB);
  unsigned short* za  = (unsigned short*)(ws + oZA);
  float* agg = (float*)(ws + oAG);
  float* P1  = (float*)(ws + oP1);
  float* P2  = (float*)(ws + oP2);
  float* Qm  = (float*)(ws + oQ);
  float* LR  = (float*)(ws + oLR);

  k_transpose_bf16<<<dim3(FEAT / 64, HIDN / 64), 256, 0, stream>>>(W1, W1T, FEAT, HIDN, HIDN);
  k_transpose_bf16<<<dim3(HIDN / 64, FEATP / 64), 256, 0, stream>>>(W2, W2T, HIDN, FEAT, FEATP);
  k_embed<<<NROWS, 256, 0, stream>>>(idx, mlt, id_emb, mult_emb, xb);
  k_agg<<<NBG, 256, 0, stream>>>(xb, agg);
  k_za<<<128, 256, 0, stream>>>(z, agg, za);
  k_gemm1<<<16 * 23, 256, 0, stream>>>(xb, DNODE, NROWS, W1T, 0, 10, P1, nullptr);
  k_gemm1<<<16 * 23, 256, 0, stream>>>(xb, DNODE, NROWS, W1T, 320, 10, P2, nullptr);
  k_gemm1<<<1 * 23, 256, 0, stream>>>(za, 832, NBG, W1T, 640, 26, Qm, b1);
  k_pq<<<NROWS, 256, 0, stream>>>(P1, Qm);
  k_zero<<<(MEDGE * NA + 255) / 256, 256, 0, stream>>>(LR, MEDGE * NA);
  k_gemm2<<<512 * 6, 256, 0, stream>>>(P1, P2, W2T, b2, W3, LR);
  k_sym<<<(MEDGE * NA + 255) / 256, 256, 0, stream>>>(LR, b3, out);
}

// Round 18
// 1132.279 us; speedup vs baseline: 1.0255x; 1.0255x over previous
//
#include <hip/hip_runtime.h>
#include <stdint.h>

// ---- problem constants ----
#define NBG   64      // graphs
#define NPER  32      // nodes per graph
#define DNODE 320
#define FEAT  1472
#define HIDN  2944
#define FEATP 1536    // FEAT padded to x128 for layer-2 N
#define NA    11
#define NROWS 2048    // NBG*NPER
#define MEDGE 65536   // NBG*NPER*NPER

typedef __attribute__((ext_vector_type(8))) short    bf16x8;
typedef __attribute__((ext_vector_type(4))) float    fv4;
typedef __attribute__((ext_vector_type(2))) float    fv2;
typedef __attribute__((ext_vector_type(4))) unsigned uiv4;

__device__ __forceinline__ unsigned short f2bf(float f) {
  unsigned u = __builtin_bit_cast(unsigned, f);
  u += 0x7fffu + ((u >> 16) & 1u);
  return (unsigned short)(u >> 16);
}
__device__ __forceinline__ float bf2f(unsigned short h) {
  unsigned u = ((unsigned)h) << 16;
  return __builtin_bit_cast(float, u);
}
__device__ __forceinline__ unsigned cvt_pk_bf16(float lo, float hi) {
  unsigned r;
  asm("v_cvt_pk_bf16_f32 %0, %1, %2" : "=v"(r) : "v"(lo), "v"(hi));
  return r;
}
// packed f32 add (VOP3P) — one instr for two adds
__device__ __forceinline__ fv2 pk_add(fv2 a, fv2 b) {
  fv2 d;
  asm("v_pk_add_f32 %0, %1, %2" : "=v"(d) : "v"(a), "v"(b));
  return d;
}
// relu on 2 packed bf16: positive bf16 sorts as positive i16; negative -> 0.
__device__ __forceinline__ unsigned pk_relu2(unsigned x, unsigned z) {
  unsigned r;
  asm("v_pk_max_i16 %0, %1, %2" : "=v"(r) : "v"(x), "v"(z));
  return r;
}
__device__ __forceinline__ fv2 lo2(fv4 v) { return __builtin_shufflevector(v, v, 0, 1); }
__device__ __forceinline__ fv2 hi2(fv4 v) { return __builtin_shufflevector(v, v, 2, 3); }
// async global->LDS, 16B per lane; lds base wave-uniform (HW adds lane*16)
__device__ __forceinline__ void gload_lds16(const void* g, void* l) {
  __builtin_amdgcn_global_load_lds((const __attribute__((address_space(1))) void*)g,
                                   (__attribute__((address_space(3))) void*)l, 16, 0, 0);
}

// ---- transpose f32 [K][N] -> bf16 [Npad][K]; rows n>=N zero-filled ----
__global__ void k_transpose_bf16(const float* __restrict__ src, unsigned short* __restrict__ dst,
                                 int K, int N, int Npad) {
  __shared__ float tile[64][65];
  int k0 = blockIdx.x * 64, n0 = blockIdx.y * 64;
  int r = threadIdx.x >> 2, cb = (threadIdx.x & 3) * 16;
  const float* srow = src + (size_t)(k0 + r) * N + n0 + cb;
#pragma unroll
  for (int c = 0; c < 16; ++c) {
    int n = n0 + cb + c;
    tile[r][cb + c] = (n < N) ? srow[c] : 0.f;
  }
  __syncthreads();
  unsigned short* drow = dst + (size_t)(n0 + r) * K + k0 + cb;
#pragma unroll
  for (int c = 0; c < 16; ++c) drow[c] = f2bf(tile[cb + c][r]);
}

// ---- embeddings -> xb bf16 [2048][320] ----
__global__ void k_embed(const int* __restrict__ idx, const int* __restrict__ mlt,
                        const float* __restrict__ id_emb, const float* __restrict__ mult_emb,
                        unsigned short* __restrict__ xb) {
  int t = blockIdx.x, c = threadIdx.x;
  int iv = idx[t], mv = mlt[t];
  xb[t * DNODE + c] = f2bf(id_emb[iv * 256 + c]);
  if (c < 64) xb[t * DNODE + 256 + c] = f2bf(mult_emb[mv * 64 + c]);
}

// ---- agg f32 [64][320] = mean over 32 nodes ----
__global__ void k_agg(const unsigned short* __restrict__ xb, float* __restrict__ agg) {
  int b = blockIdx.x;
  for (int d = threadIdx.x; d < DNODE; d += 256) {
    float s = 0.f;
    for (int i = 0; i < NPER; ++i) s += bf2f(xb[(b * NPER + i) * DNODE + d]);
    agg[b * DNODE + d] = s * (1.f / 32.f);
  }
}

// ---- za bf16 [128][832] = [z | agg], rows 64..127 zero ----
__global__ void k_za(const float* __restrict__ z, const float* __restrict__ agg,
                     unsigned short* __restrict__ za) {
  int b = blockIdx.x;
  for (int c = threadIdx.x; c < 832; c += 256) {
    unsigned short v = 0;
    if (b < NBG) v = (c < 512) ? f2bf(z[b * 512 + c]) : f2bf(agg[b * DNODE + (c - 512)]);
    za[b * 832 + c] = v;
  }
}

// ---- layer-1 GEMM: C[M][2944] (f32) = A(bf16,[M][sA] slice) @ W1T(bf16 [2944][1472])^T ----
__global__ void k_gemm1(const unsigned short* __restrict__ A, int sA, int Mrows,
                        const unsigned short* __restrict__ W1T, int kOff, int Ksteps,
                        float* __restrict__ C, const float* __restrict__ bias) {
  __shared__ alignas(16) unsigned short Als[128 * 32];
  __shared__ alignas(16) unsigned short Bls[128 * 32];
  int bx = blockIdx.x;
  int mt = bx / 23, nc = bx - mt * 23;
  int m0 = mt * 128, n0 = nc * 128;
  int tid = threadIdx.x, lane = tid & 63, w = tid >> 6;

  fv4 acc[4][4] = {};
  for (int kt = 0; kt < Ksteps; ++kt) {
    int k0 = kt * 32;
    __syncthreads();
#pragma unroll
    for (int q = 0; q < 2; ++q) {
      int seg = w * 2 + q;
      int row = seg * 16 + (lane >> 2);
      int col = (lane & 3) * 8;
      gload_lds16(A + (size_t)(m0 + row) * sA + k0 + col, &Als[seg * 512]);
      gload_lds16(W1T + (size_t)(n0 + row) * FEAT + kOff + k0 + col, &Bls[seg * 512]);
    }
    __syncthreads();
    bf16x8 aF[4], bF[4];
#pragma unroll
    for (int mf = 0; mf < 4; ++mf)
      aF[mf] = *(const bf16x8*)&Als[((w >> 1) * 64 + mf * 16 + (lane & 15)) * 32 + (lane >> 4) * 8];
#pragma unroll
    for (int nf = 0; nf < 4; ++nf)
      bF[nf] = *(const bf16x8*)&Bls[((w & 1) * 64 + nf * 16 + (lane & 15)) * 32 + (lane >> 4) * 8];
#pragma unroll
    for (int mf = 0; mf < 4; ++mf)
#pragma unroll
      for (int nf = 0; nf < 4; ++nf)
        acc[mf][nf] = __builtin_amdgcn_mfma_f32_16x16x32_bf16(aF[mf], bF[nf], acc[mf][nf], 0, 0, 0);
  }
  int mq = (w >> 1) * 64, nq = (w & 1) * 64;
#pragma unroll
  for (int mf = 0; mf < 4; ++mf)
#pragma unroll
    for (int nf = 0; nf < 4; ++nf) {
      int n = n0 + nq + nf * 16 + (lane & 15);
      float bv = bias ? bias[n] : 0.f;
#pragma unroll
      for (int r = 0; r < 4; ++r) {
        int m = m0 + mq + mf * 16 + (lane >> 4) * 4 + r;
        if (m < Mrows) C[(size_t)m * HIDN + n] = acc[mf][nf][r] + bv;
      }
    }
}

// ---- PQ1 = P1 + Q[b] (in place on P1; Q already includes b1) ----
__global__ void k_pq(float* __restrict__ P1, const float* __restrict__ Q) {
  int r = blockIdx.x;
  const float* q = Q + (size_t)(r >> 5) * HIDN;
  float* p = P1 + (size_t)r * HIDN;
  for (int n = threadIdx.x; n < HIDN; n += 256) p[n] += q[n];
}

__global__ void k_zero(float* __restrict__ p, int n) {
  int i = blockIdx.x * 256 + threadIdx.x;
  if (i < n) p[i] = 0.f;
}

// ---- layer-2 GEMM fused with layer-3 partial, N=256 per block (champion) ----
// Session champion (R11/R16, 1133 us total, re-verified twice): 3072 blocks,
// 2-barrier double-buffered staging, on-the-fly A-construct with packed math,
// 32 MFMA per wave-step, atomic epilogue, NC-MAJOR XCD dispatch order (each
// XCD's time-sequential blocks share one 1.5 MB W2T panel -> L2-resident;
// FETCH 497->246 MB). Verified multi-axis local floor: schedule (R1/R7/R10),
// chain pipelining (R17), traffic (R6/R8), occupancy (R12-14), MFMA shape
// (R15) all null or negative around this point.
// LDS: B[2][16384] @0 | P2s[2][4096] @32768 | PQ1s[2][1024] @40960 = 43008
__global__ __launch_bounds__(256, 2)
void k_gemm2(const float* __restrict__ PQ1, const float* __restrict__ P2,
             const unsigned short* __restrict__ W2T,
             const float* __restrict__ b2, const float* __restrict__ W3,
             float* __restrict__ Lout) {
  __shared__ alignas(16) unsigned char LB[43008];
  int raw = blockIdx.x;
  int g = (raw & 7) * 384 + (raw >> 3);   // bijective: 3072 = 8 * 384
  int nc2 = g / 512;                      // panel index: constant per XCD span
  int mt  = g - nc2 * 512;                // sequential m-tiles within a panel
  int m0 = mt * 128, n0 = nc2 * 256;
  int tid = threadIdx.x, lane = tid & 63, w = tid >> 6;
  int bG = m0 >> 10;
  int i0 = (m0 >> 5) & 31;
  int ks = lane >> 4;
  int r  = lane & 15;

  const int swcolB = ((lane & 3) ^ ((lane >> 3) & 3)) * 8;
  const int swcolP = (((lane >> 1) & 3) ^ ((lane >> 3) & 3)) * 8 + (lane & 1) * 4;

  auto STAGEB = [&](int kt, int buf) {
#pragma unroll
    for (int q = 0; q < 4; ++q) {
      int seg = w * 4 + q;
      int row = seg * 16 + (lane >> 2);
      gload_lds16(W2T + (size_t)(n0 + row) * HIDN + kt * 32 + swcolB,
                  LB + buf * 16384 + seg * 1024);
    }
  };
  auto STAGESRC = [&](int kt, int buf) {
    gload_lds16(P2 + (size_t)(bG * NPER + 8 * w + (lane >> 3)) * HIDN + kt * 32 + swcolP,
                LB + 32768 + buf * 4096 + w * 1024);
    if (w == 0)
      gload_lds16(PQ1 + (size_t)(bG * NPER + i0 + (lane >> 3)) * HIDN + kt * 32 + (lane & 7) * 4,
                  LB + 40960 + buf * 1024);
  };

  fv4 acc[4][8] = {};
  unsigned z0 = 0;
  asm volatile("" : "+v"(z0));   // keep zero in a VGPR for pk_max

  STAGEB(0, 0);
  STAGESRC(0, 0);
  __syncthreads();

  int il0 = (w >> 1) * 2;
  for (int kt = 0; kt < 92; ++kt) {
    int cur = kt & 1, nxt = cur ^ 1;
    if (kt < 91) { STAGEB(kt + 1, nxt); STAGESRC(kt + 1, nxt); }

    const unsigned char* Bb = LB + cur * 16384;
    const unsigned char* Pb = LB + 32768 + cur * 4096;
    const unsigned char* Qb = LB + 40960 + cur * 1024;

    int psw = (ks ^ (r & 3)) * 32;
    fv4 q0[2], q1[2], p0[2], p1[2];
#pragma unroll
    for (int h = 0; h < 2; ++h) {
      q0[h] = *(const fv4*)(Qb + il0 * 128 + ks * 32 + h * 16);        // broadcast
      q1[h] = *(const fv4*)(Qb + (il0 + 1) * 128 + ks * 32 + h * 16);  // broadcast
      p0[h] = *(const fv4*)(Pb + r * 128 + psw + h * 16);
      p1[h] = *(const fv4*)(Pb + (16 + r) * 128 + psw + h * 16);
    }
    bf16x8 bF[8];
#pragma unroll
    for (int nf = 0; nf < 8; ++nf) {
      int brow = (w & 1) * 128 + nf * 16 + r;
      int slot = ks ^ ((brow >> 1) & 3);
      bF[nf] = *(const bf16x8*)(Bb + brow * 64 + slot * 16);
    }

    // construct A fragments: bf16(PQ1[i]+P2[j]) then packed relu
    bf16x8 aF[4];
#pragma unroll
    for (int mf = 0; mf < 4; ++mf) {
      fv4 qa0 = (mf & 2) ? q1[0] : q0[0];
      fv4 qa1 = (mf & 2) ? q1[1] : q0[1];
      fv4 pa0 = (mf & 1) ? p1[0] : p0[0];
      fv4 pa1 = (mf & 1) ? p1[1] : p0[1];
      fv2 s00 = pk_add(lo2(qa0), lo2(pa0));
      fv2 s01 = pk_add(hi2(qa0), hi2(pa0));
      fv2 s10 = pk_add(lo2(qa1), lo2(pa1));
      fv2 s11 = pk_add(hi2(qa1), hi2(pa1));
      uiv4 u;
      u[0] = pk_relu2(cvt_pk_bf16(s00[0], s00[1]), z0);
      u[1] = pk_relu2(cvt_pk_bf16(s01[0], s01[1]), z0);
      u[2] = pk_relu2(cvt_pk_bf16(s10[0], s10[1]), z0);
      u[3] = pk_relu2(cvt_pk_bf16(s11[0], s11[1]), z0);
      aF[mf] = __builtin_bit_cast(bf16x8, u);
    }

#pragma unroll
    for (int nf = 0; nf < 8; ++nf)
#pragma unroll
      for (int mf = 0; mf < 4; ++mf)
        acc[mf][nf] = __builtin_amdgcn_mfma_f32_16x16x32_bf16(aF[mf], bF[nf], acc[mf][nf], 0, 0, 0);
    __syncthreads();
  }

  // epilogue: h2 = relu(acc + b2); partial logits = h2 @ W3 chunk (128 n-cols
  // per wave); wave shfl reduce; cross-wave LDS reduce; atomicAdd.
  float* red = (float*)LB;
  int nq = (w & 1) * 128;
#pragma unroll
  for (int mf = 0; mf < 4; ++mf) {
    float s[4][NA];
#pragma unroll
    for (int rr = 0; rr < 4; ++rr)
#pragma unroll
      for (int a = 0; a < NA; ++a) s[rr][a] = 0.f;
#pragma unroll
    for (int nf = 0; nf < 8; ++nf) {
      int n = n0 + nq + nf * 16 + r;
      if (n < FEAT) {  // boundary multiple of 16 -> uniform per nf
        float bv = b2[n];
        float w3r[NA];
#pragma unroll
        for (int a = 0; a < NA; ++a) w3r[a] = W3[n * NA + a];
#pragma unroll
        for (int rr = 0; rr < 4; ++rr) {
          float h = fmaxf(acc[mf][nf][rr] + bv, 0.f);
#pragma unroll
          for (int a = 0; a < NA; ++a) s[rr][a] += h * w3r[a];
        }
      }
    }
#pragma unroll
    for (int off = 1; off < 16; off <<= 1)
#pragma unroll
      for (int rr = 0; rr < 4; ++rr)
#pragma unroll
        for (int a = 0; a < NA; ++a) s[rr][a] += __shfl_xor(s[rr][a], off, 64);
    int a = r;
    if (a < NA) {
#pragma unroll
      for (int rr = 0; rr < 4; ++rr)
        red[w * 704 + (mf * 16 + ks * 4 + rr) * NA + a] = s[rr][a];
    }
  }
  __syncthreads();
  for (int e = tid; e < 128 * NA; e += 256) {
    int row = e / NA, a = e - row * NA;
    int wr = row >> 6, rr = row & 63;
    float v = red[(wr * 2 + 0) * 704 + rr * NA + a] + red[(wr * 2 + 1) * 704 + rr * NA + a];
    atomicAdd(&Lout[(size_t)(m0 + row) * NA + a], v);
  }
}

// ---- symmetrize + b3 ----
__global__ void k_sym(const float* __restrict__ Lraw, const float* __restrict__ b3,
                      float* __restrict__ out) {
  int e = blockIdx.x * 256 + threadIdx.x;
  if (e >= MEDGE * NA) return;
  int m = e / NA, a = e - m * NA;
  int msw = (m & ~1023) | ((m & 31) << 5) | ((m >> 5) & 31);
  out[e] = 0.5f * (Lraw[e] + Lraw[(size_t)msw * NA + a]) + b3[a];
}

extern "C" void kernel_launch(void* const* d_in, const int* in_sizes, int n_in,
                              void* d_out, int out_size, void* d_ws, size_t ws_size,
                              hipStream_t stream) {
  const int*   idx      = (const int*)d_in[0];
  const int*   mlt      = (const int*)d_in[1];
  const float* z        = (const float*)d_in[2];
  const float* id_emb   = (const float*)d_in[3];
  const float* mult_emb = (const float*)d_in[4];
  const float* W1       = (const float*)d_in[5];
  const float* b1       = (const float*)d_in[6];
  const float* W2       = (const float*)d_in[7];
  const float* b2       = (const float*)d_in[8];
  const float* W3       = (const float*)d_in[9];
  const float* b3       = (const float*)d_in[10];
  float* out = (float*)d_out;

  uint8_t* ws = (uint8_t*)d_ws;
  size_t o = 0;
  auto alloc = [&](size_t bytes) { size_t r = o; o += (bytes + 255) & ~(size_t)255; return r; };
  size_t oW1T = alloc((size_t)HIDN * FEAT * 2);       // bf16 [2944][1472]
  size_t oW2T = alloc((size_t)FEATP * HIDN * 2);      // bf16 [1536][2944]
  size_t oXB  = alloc((size_t)NROWS * DNODE * 2);     // bf16 [2048][320]
  size_t oZA  = alloc((size_t)128 * 832 * 2);         // bf16 [128][832]
  size_t oAG  = alloc((size_t)NBG * DNODE * 4);       // f32  [64][320]
  size_t oP1  = alloc((size_t)NROWS * HIDN * 4);      // f32  [2048][2944]
  size_t oP2  = alloc((size_t)NROWS * HIDN * 4);
  size_t oQ   = alloc((size_t)NBG * HIDN * 4);
  size_t oLR  = alloc((size_t)MEDGE * NA * 4);        // single f32 slice
  if (ws_size < o) return;  // insufficient workspace (71.2 MB, known to fit)

  unsigned short* W1T = (unsigned short*)(ws + oW1T);
  unsigned short* W2T = (unsigned short*)(ws + oW2T);
  unsigned short* xb  = (unsigned short*)(ws + oXB);
  unsigned short* za  = (unsigned short*)(ws + oZA);
  float* agg = (float*)(ws + oAG);
  float* P1  = (float*)(ws + oP1);
  float* P2  = (float*)(ws + oP2);
  float* Qm  = (float*)(ws + oQ);
  float* LR  = (float*)(ws + oLR);

  k_transpose_bf16<<<dim3(FEAT / 64, HIDN / 64), 256, 0, stream>>>(W1, W1T, FEAT, HIDN, HIDN);
  k_transpose_bf16<<<dim3(HIDN / 64, FEATP / 64), 256, 0, stream>>>(W2, W2T, HIDN, FEAT, FEATP);
  k_embed<<<NROWS, 256, 0, stream>>>(idx, mlt, id_emb, mult_emb, xb);
  k_agg<<<NBG, 256, 0, stream>>>(xb, agg);
  k_za<<<128, 256, 0, stream>>>(z, agg, za);
  k_gemm1<<<16 * 23, 256, 0, stream>>>(xb, DNODE, NROWS, W1T, 0, 10, P1, nullptr);
  k_gemm1<<<16 * 23, 256, 0, stream>>>(xb, DNODE, NROWS, W1T, 320, 10, P2, nullptr);
  k_gemm1<<<1 * 23, 256, 0, stream>>>(za, 832, NBG, W1T, 640, 26, Qm, b1);
  k_pq<<<NROWS, 256, 0, stream>>>(P1, Qm);
  k_zero<<<(MEDGE * NA + 255) / 256, 256, 0, stream>>>(LR, MEDGE * NA);
  k_gemm2<<<512 * 6, 256, 0, stream>>>(P1, P2, W2T, b2, W3, LR);
  k_sym<<<(MEDGE * NA + 255) / 256, 256, 0, stream>>>(LR, b3, out);
}